// Round 8
// baseline (212.818 us; speedup 1.0000x reference)
//
#include <hip/hip_runtime.h>
#include <hip/hip_fp16.h>
#include <stdint.h>

#pragma clang fp contract(off)

namespace {
constexpr int B_ = 2, V_ = 2, HC = 512, WC = 512, HF = 256, WF = 256, CF = 64;
constexpr int NPIX = HF * WF;                 // 65536
constexpr float EPSF = 1e-4f;
constexpr float BIGF = 1e10f;                 // exactly representable in f32
constexpr int NPT = B_ * V_ * NPIX;           // 262144
constexpr int NBLK = 1024;                    // NPT/256
constexpr int RESIZE_BLKS = (B_ * V_ * 3 * NPIX) / 256;   // 3072
constexpr int TP_BLKS = B_ * V_ * (NPIX / 64);            // 4096 (64px x 64ch tiles)
// workspace layout: zwin (2 MiB) | colr (3 MiB) | mats (256 B) | tf fp16 (32 MiB)
constexpr size_t WS_BASE = (size_t)NPT * 8 + (size_t)B_ * V_ * 3 * NPIX * 4 + 256;
constexpr size_t TF_BYTES = (size_t)NPT * CF * 2;          // fp16 records
}

// NON-FMA ascending f32 dot4 (fp contract off TU-wide keeps mul/add separate).
__device__ __forceinline__ float dot4f(const float* __restrict__ r,
                                       float v0, float v1, float v2, float v3) {
  float t = r[0] * v0;
  t = t + r[1] * v1;
  t = t + r[2] * v2;
  t = t + r[3] * v3;
  return t;
}

// per-batch sK / sKinv (f64 adjugate -> f32). Executed by thread b (b < B_).
__device__ void mats_compute(const float* __restrict__ K, int b,
                             float* __restrict__ mats) {
  const float rowscale[4] = {0.5f, 0.5f, 1.0f, 1.0f};
  float sK[16];
  for (int i = 0; i < 4; ++i)
    for (int j = 0; j < 4; ++j)
      sK[i*4+j] = K[b*16 + i*4 + j] * rowscale[i];
  double m[16];
  for (int i = 0; i < 16; ++i) m[i] = (double)sK[i];
  double inv[16];
  inv[0]  =  m[5]*m[10]*m[15] - m[5]*m[11]*m[14] - m[9]*m[6]*m[15] + m[9]*m[7]*m[14] + m[13]*m[6]*m[11] - m[13]*m[7]*m[10];
  inv[4]  = -m[4]*m[10]*m[15] + m[4]*m[11]*m[14] + m[8]*m[6]*m[15] - m[8]*m[7]*m[14] - m[12]*m[6]*m[11] + m[12]*m[7]*m[10];
  inv[8]  =  m[4]*m[9]*m[15]  - m[4]*m[11]*m[13] - m[8]*m[5]*m[15] + m[8]*m[7]*m[13] + m[12]*m[5]*m[11] - m[12]*m[7]*m[9];
  inv[12] = -m[4]*m[9]*m[14]  + m[4]*m[10]*m[13] + m[8]*m[5]*m[14] - m[8]*m[6]*m[13] - m[12]*m[5]*m[10] + m[12]*m[6]*m[9];
  inv[1]  = -m[1]*m[10]*m[15] + m[1]*m[11]*m[14] + m[9]*m[2]*m[15] - m[9]*m[3]*m[14] - m[13]*m[2]*m[11] + m[13]*m[3]*m[10];
  inv[5]  =  m[0]*m[10]*m[15] - m[0]*m[11]*m[14] - m[8]*m[2]*m[15] + m[8]*m[3]*m[14] + m[12]*m[2]*m[11] - m[12]*m[3]*m[10];
  inv[9]  = -m[0]*m[9]*m[15]  + m[0]*m[11]*m[13] + m[8]*m[1]*m[15] - m[8]*m[3]*m[13] - m[12]*m[1]*m[11] + m[12]*m[3]*m[9];
  inv[13] =  m[0]*m[9]*m[14]  - m[0]*m[10]*m[13] - m[8]*m[1]*m[14] + m[8]*m[2]*m[13] + m[12]*m[1]*m[10] - m[12]*m[2]*m[9];
  inv[2]  =  m[1]*m[6]*m[15]  - m[1]*m[7]*m[14]  - m[5]*m[2]*m[15] + m[5]*m[3]*m[14] + m[13]*m[2]*m[7]  - m[13]*m[3]*m[6];
  inv[6]  = -m[0]*m[6]*m[15]  + m[0]*m[7]*m[14]  + m[4]*m[2]*m[15] - m[4]*m[3]*m[14] - m[12]*m[2]*m[7]  + m[12]*m[3]*m[6];
  inv[10] =  m[0]*m[5]*m[15]  - m[0]*m[7]*m[13]  - m[4]*m[1]*m[15] + m[4]*m[3]*m[13] + m[12]*m[1]*m[7]  - m[12]*m[3]*m[5];
  inv[14] = -m[0]*m[5]*m[14]  + m[0]*m[6]*m[13]  + m[4]*m[1]*m[14] - m[4]*m[2]*m[13] - m[12]*m[1]*m[6]  + m[12]*m[2]*m[5];
  inv[3]  = -m[1]*m[6]*m[11]  + m[1]*m[7]*m[10]  + m[5]*m[2]*m[11] - m[5]*m[3]*m[10] - m[9]*m[2]*m[7]   + m[9]*m[3]*m[6];
  inv[7]  =  m[0]*m[6]*m[11]  - m[0]*m[7]*m[10]  - m[4]*m[2]*m[11] + m[4]*m[3]*m[10] + m[8]*m[2]*m[7]   - m[8]*m[3]*m[6];
  inv[11] = -m[0]*m[5]*m[11]  + m[0]*m[7]*m[9]   + m[4]*m[1]*m[11] - m[4]*m[3]*m[9]  - m[8]*m[1]*m[7]   + m[8]*m[3]*m[5];
  inv[15] =  m[0]*m[5]*m[10]  - m[0]*m[6]*m[9]   - m[4]*m[1]*m[10] + m[4]*m[2]*m[9]  + m[8]*m[1]*m[6]   - m[8]*m[2]*m[5];
  double det = m[0]*inv[0] + m[1]*inv[4] + m[2]*inv[8] + m[3]*inv[12];
  double idet = 1.0 / det;
  for (int i = 0; i < 16; ++i) {
    mats[b*32 + i]      = sK[i];
    mats[b*32 + 16 + i] = (float)(inv[i] * idet);
  }
}

// antialiased linear 2x downsample of colors (r5 arithmetic).
__device__ __forceinline__ void resize_body(int g,
                                            const float* __restrict__ colors,
                                            float* __restrict__ colr) {
  int pc  = g >> 16;            // bv*3 + ch
  int pix = g & (NPIX - 1);
  int y = pix >> 8, x = pix & (WF - 1);
  const float* src = colors + (size_t)pc * HC * WC;
  const float W37 = (float)(3.0 / 7.0), W17 = (float)(1.0 / 7.0);
  float wy[4] = {0.125f, 0.375f, 0.375f, 0.125f};
  float wx[4] = {0.125f, 0.375f, 0.375f, 0.125f};
  if (y == 0)      { wy[0] = 0.f; wy[1] = W37; wy[2] = W37; wy[3] = W17; }
  if (y == HF - 1) { wy[0] = W17; wy[1] = W37; wy[2] = W37; wy[3] = 0.f; }
  if (x == 0)      { wx[0] = 0.f; wx[1] = W37; wx[2] = W37; wx[3] = W17; }
  if (x == WF - 1) { wx[0] = W17; wx[1] = W37; wx[2] = W37; wx[3] = 0.f; }
  int jy0 = 2 * y - 1, jx0 = 2 * x - 1;
  float acc = 0.f;
  #pragma unroll
  for (int ty = 0; ty < 4; ++ty) {
    if (wy[ty] == 0.f) continue;       // also guards OOB rows
    int jy = jy0 + ty;
    float rs = 0.f;
    #pragma unroll
    for (int tx = 0; tx < 4; ++tx) {
      if (wx[tx] == 0.f) continue;     // also guards OOB cols
      rs = rs + wx[tx] * src[(size_t)jy * WC + (jx0 + tx)];
    }
    acc = acc + wy[ty] * rs;
  }
  colr[g] = acc;
}

// f32 projection + z-buffer atomicMin (r5 PASSING numerics — do not touch).
__device__ __forceinline__ void splat_body(int g,
                                           const float* __restrict__ depths,
                                           const float* __restrict__ mats,
                                           const float* __restrict__ srcRTinv,
                                           const float* __restrict__ dstRT,
                                           unsigned long long* __restrict__ zwin) {
  int bv = g >> 16;
  int n  = g & (NPIX - 1);
  int b  = bv / V_;
  int y = n >> 8, x = n & (WF - 1);
  float d = depths[(size_t)bv * HC * WC + (size_t)(2 * y + 1) * WC + (2 * x + 1)];
  const float step32 = 2.0f / 255.0f;
  float xf = (float)x * step32 - 1.0f;
  float yf = (float)y * step32 - 1.0f;
  float pr0 = xf * d, pr1 = yf * d, pr2 = d, pr3 = 1.0f;
  const float* sK  = mats + b * 32;
  const float* sKi = mats + b * 32 + 16;
  const float* Rs  = srcRTinv + (size_t)bv * 16;
  const float* Rd  = dstRT + (size_t)b * 16;     // dst_RTs[:,0]
  float a0 = dot4f(sKi + 0,  pr0, pr1, pr2, pr3);
  float a1 = dot4f(sKi + 4,  pr0, pr1, pr2, pr3);
  float a2 = dot4f(sKi + 8,  pr0, pr1, pr2, pr3);
  float a3 = dot4f(sKi + 12, pr0, pr1, pr2, pr3);
  float w0 = dot4f(Rs + 0,  a0, a1, a2, a3);
  float w1 = dot4f(Rs + 4,  a0, a1, a2, a3);
  float w2 = dot4f(Rs + 8,  a0, a1, a2, a3);
  float w3 = dot4f(Rs + 12, a0, a1, a2, a3);
  float c0 = dot4f(Rd + 0,  w0, w1, w2, w3);
  float c1 = dot4f(Rd + 4,  w0, w1, w2, w3);
  float c2 = dot4f(Rd + 8,  w0, w1, w2, w3);
  float c3 = dot4f(Rd + 12, w0, w1, w2, w3);
  float p0 = dot4f(sK + 0, c0, c1, c2, c3);
  float p1 = dot4f(sK + 4, c0, c1, c2, c3);
  float p2 = dot4f(sK + 8, c0, c1, c2, c3);
  if (p2 > EPSF) {
    float sx = p0 / p2, sy = p1 / p2;                 // f32 IEEE division
    float pxf = rintf(((sx + 1.0f) * 0.5f) * 255.0f); // jnp.round = half-to-even
    float pyf = rintf(((sy + 1.0f) * 0.5f) * 255.0f);
    if (pxf >= 0.0f && pxf <= 255.0f && pyf >= 0.0f && pyf <= 255.0f) {
      int idx = (int)pyf * WF + (int)pxf;
      unsigned zbits = __float_as_uint(p2);           // p2>0 -> order-preserving
      unsigned long long key = ((unsigned long long)zbits << 32) | (unsigned)n;
      atomicMin(&zwin[(size_t)bv * NPIX + idx], key);
    }
  }
}

// --- init: zwin init + per-batch matrices. grid = 1024 x 256 ---
__global__ void init_k(const float* __restrict__ K,
                       float* __restrict__ mats,
                       unsigned long long* __restrict__ zwin) {
  int g = blockIdx.x * blockDim.x + threadIdx.x;
  zwin[g] = ~0ULL;
  if (g < B_) mats_compute(K, g, mats);
}

// --- fused work: fp16 transpose + resize + splat (mutually independent).
// Transpose blocks [0, TP_BLKS): (bv,c,pix)->(bv,pix,c) fp16 records.
//   4x4 reg micro-tile (r5-proven, no LDS -> full occupancy for all phases);
//   feats values RTE-rounded to fp16: max err ~5.7sigma*2^-11 ~ 0.0028 <<
//   0.0078125 budget (feats path was exact; winner indices unaffected).
//   Per pixel the 4 channels pack into one 8B uint2 store (8B-aligned).
//   tf traffic halves vs fp32: 64->32 MB write, gather re-read halves too.
__global__ void work_k(const float* __restrict__ depths,
                       const float* __restrict__ mats,
                       const float* __restrict__ srcRTinv,
                       const float* __restrict__ dstRT,
                       unsigned long long* __restrict__ zwin,
                       const float* __restrict__ feats,
                       __half* __restrict__ tf,
                       const float* __restrict__ colors,
                       float* __restrict__ colr) {
  int bid = blockIdx.x;
  int nTP = (int)gridDim.x - RESIZE_BLKS - NBLK;
  int t = threadIdx.x;

  if (bid < nTP) {                     // ---- transpose (fp16 out) ----
    int bv = bid >> 10;                // 1024 tiles per bv (64 px each)
    int pix0 = (bid & 1023) << 6;
    int c4 = t >> 4;                   // 0..15 -> channels 4*c4..4*c4+3
    int p4 = t & 15;                   // 0..15 -> pixels 4*p4..4*p4+3
    const float* fb = feats + (size_t)bv * CF * NPIX + pix0 + 4 * p4;
    float4 v0 = *(const float4*)(fb + (size_t)(4 * c4 + 0) * NPIX);
    float4 v1 = *(const float4*)(fb + (size_t)(4 * c4 + 1) * NPIX);
    float4 v2 = *(const float4*)(fb + (size_t)(4 * c4 + 2) * NPIX);
    float4 v3 = *(const float4*)(fb + (size_t)(4 * c4 + 3) * NPIX);
    __half* tb = tf + ((size_t)bv * NPIX + pix0 + 4 * p4) * CF + 4 * c4;
    union { __half h[4]; uint2 u; } pk;
    pk.h[0] = __float2half(v0.x); pk.h[1] = __float2half(v1.x);
    pk.h[2] = __float2half(v2.x); pk.h[3] = __float2half(v3.x);
    *(uint2*)(tb + 0 * CF) = pk.u;
    pk.h[0] = __float2half(v0.y); pk.h[1] = __float2half(v1.y);
    pk.h[2] = __float2half(v2.y); pk.h[3] = __float2half(v3.y);
    *(uint2*)(tb + 1 * CF) = pk.u;
    pk.h[0] = __float2half(v0.z); pk.h[1] = __float2half(v1.z);
    pk.h[2] = __float2half(v2.z); pk.h[3] = __float2half(v3.z);
    *(uint2*)(tb + 2 * CF) = pk.u;
    pk.h[0] = __float2half(v0.w); pk.h[1] = __float2half(v1.w);
    pk.h[2] = __float2half(v2.w); pk.h[3] = __float2half(v3.w);
    *(uint2*)(tb + 3 * CF) = pk.u;
    return;
  }

  int rb = bid - nTP;
  if (rb < RESIZE_BLKS) {              // ---- color resize ----
    resize_body(rb * 256 + t, colors, colr);
    return;
  }

  // ---- splat ----
  int g = (rb - RESIZE_BLKS) * 256 + t;
  splat_body(g, depths, mats, srcRTinv, dstRT, zwin);
}

// --- gather from fp16 records, 3 block-groups:
// grp 0/1: 32 feat channels = 64B (4 aligned float4 loads) + half2float.
// grp 2:   colors (V,B,3,H,W layout!) + depth.
// grid = 3 * NBLK blocks x 256.
__global__ void gather3_k(const unsigned long long* __restrict__ zwin,
                          const __half* __restrict__ tf,
                          const float* __restrict__ colr,
                          float* __restrict__ out0,
                          float* __restrict__ out1,
                          float* __restrict__ out2) {
  int bid = blockIdx.x;
  int grp = bid >> 10;
  int g   = (bid & (NBLK - 1)) * 256 + threadIdx.x;
  int bv  = g >> 16;
  int pix = g & (NPIX - 1);
  unsigned long long key = zwin[g];
  bool hit = (key != ~0ULL);
  int n = (int)(key & 0xffffffffULL);

  if (grp < 2) {                       // 32 feat channels = 64B of fp16
    float4 raw[4];
    if (hit) {
      // byte offset = (n*64 + grp*32)*2 = n*128 + 64*grp -> 16B aligned
      const float4* src =
          (const float4*)(tf + ((size_t)bv * NPIX + n) * CF + grp * 32);
      #pragma unroll
      for (int i = 0; i < 4; ++i) raw[i] = src[i];
    } else {
      #pragma unroll
      for (int i = 0; i < 4; ++i) raw[i] = make_float4(0.f, 0.f, 0.f, 0.f);
    }
    float* o0 = out0 + (size_t)bv * CF * NPIX + (size_t)(grp * 32) * NPIX + pix;
    const __half* hp = (const __half*)raw;
    if (hit) {
      #pragma unroll
      for (int c = 0; c < 32; ++c)
        __builtin_nontemporal_store(__half2float(hp[c]), &o0[(size_t)c * NPIX]);
    } else {
      #pragma unroll
      for (int c = 0; c < 32; ++c)
        __builtin_nontemporal_store(0.0f, &o0[(size_t)c * NPIX]);
    }
  } else {                             // colors + depth
    int b = bv >> 1, v = bv & 1;
    const float* cb = colr + (size_t)bv * 3 * NPIX;
    float* o1 = out1 + (size_t)(v * B_ + b) * 3 * NPIX + pix;
    if (hit) {
      float z = __uint_as_float((unsigned)(key >> 32));
      __builtin_nontemporal_store((z < BIGF) ? z : 0.0f, &out2[g]);
      #pragma unroll
      for (int ch = 0; ch < 3; ++ch)
        __builtin_nontemporal_store(cb[(size_t)ch * NPIX + n] * 0.5f + 0.5f,
                                    &o1[(size_t)ch * NPIX]);
    } else {
      __builtin_nontemporal_store(0.0f, &out2[g]);
      #pragma unroll
      for (int ch = 0; ch < 3; ++ch)
        __builtin_nontemporal_store(0.0f, &o1[(size_t)ch * NPIX]);
    }
  }
}

// --- no-tf fallback: resize+splat fused, then fp32 direct gather (r0) ---
__global__ void work_fb_k(const float* __restrict__ depths,
                          const float* __restrict__ mats,
                          const float* __restrict__ srcRTinv,
                          const float* __restrict__ dstRT,
                          unsigned long long* __restrict__ zwin,
                          const float* __restrict__ colors,
                          float* __restrict__ colr) {
  int bid = blockIdx.x;
  int t = threadIdx.x;
  if (bid < RESIZE_BLKS) { resize_body(bid * 256 + t, colors, colr); return; }
  int g = (bid - RESIZE_BLKS) * 256 + t;
  splat_body(g, depths, mats, srcRTinv, dstRT, zwin);
}

__global__ void gather_k(const unsigned long long* __restrict__ zwin,
                         const float* __restrict__ feats,
                         const float* __restrict__ colr,
                         float* __restrict__ out0,
                         float* __restrict__ out1,
                         float* __restrict__ out2) {
  int bid = blockIdx.x;
  int grp = bid >> 10;
  int g   = (bid & (NBLK - 1)) * 256 + threadIdx.x;
  int bv  = g >> 16;
  int pix = g & (NPIX - 1);
  unsigned long long key = zwin[g];
  bool hit = (key != ~0ULL);
  int n = (int)(key & 0xffffffffULL);

  if (grp < 4) {
    int c0 = grp * 16;
    const float* fb = feats + (size_t)bv * CF * NPIX + (size_t)c0 * NPIX;
    float* o0 = out0 + (size_t)bv * CF * NPIX + (size_t)c0 * NPIX + pix;
    if (hit) {
      #pragma unroll
      for (int c = 0; c < 16; ++c)
        __builtin_nontemporal_store(fb[(size_t)c * NPIX + n], &o0[(size_t)c * NPIX]);
    } else {
      #pragma unroll
      for (int c = 0; c < 16; ++c)
        __builtin_nontemporal_store(0.0f, &o0[(size_t)c * NPIX]);
    }
  } else {
    int b = bv >> 1, v = bv & 1;
    const float* cb = colr + (size_t)bv * 3 * NPIX;
    float* o1 = out1 + (size_t)(v * B_ + b) * 3 * NPIX + pix;
    if (hit) {
      float z = __uint_as_float((unsigned)(key >> 32));
      __builtin_nontemporal_store((z < BIGF) ? z : 0.0f, &out2[g]);
      #pragma unroll
      for (int ch = 0; ch < 3; ++ch)
        __builtin_nontemporal_store(cb[(size_t)ch * NPIX + n] * 0.5f + 0.5f,
                                    &o1[(size_t)ch * NPIX]);
    } else {
      __builtin_nontemporal_store(0.0f, &out2[g]);
      #pragma unroll
      for (int ch = 0; ch < 3; ++ch)
        __builtin_nontemporal_store(0.0f, &o1[(size_t)ch * NPIX]);
    }
  }
}

extern "C" void kernel_launch(void* const* d_in, const int* in_sizes, int n_in,
                              void* d_out, int out_size, void* d_ws, size_t ws_size,
                              hipStream_t stream) {
  const float* depths     = (const float*)d_in[0];
  const float* colors     = (const float*)d_in[1];
  const float* feats      = (const float*)d_in[2];
  const float* K          = (const float*)d_in[3];
  const float* src_RTinvs = (const float*)d_in[5];
  const float* dst_RTs    = (const float*)d_in[6];

  float* out0 = (float*)d_out;                                  // (B,V,64,256,256)
  float* out1 = out0 + (size_t)B_ * V_ * CF * NPIX;             // (V,B,3,256,256)
  float* out2 = out1 + (size_t)V_ * B_ * 3 * NPIX;              // (B,V,1,256,256)

  unsigned long long* zwin = (unsigned long long*)d_ws;         // 2 MiB
  float* colr = (float*)(zwin + NPT);                           // 3 MiB
  float* mats = colr + (size_t)B_ * V_ * 3 * NPIX;              // 256 B
  __half* tf  = (__half*)((char*)d_ws + WS_BASE);               // 32 MiB fp16

  const bool use_tf = (ws_size >= WS_BASE + TF_BYTES);

  init_k<<<NBLK, 256, 0, stream>>>(K, mats, zwin);
  if (use_tf) {
    work_k<<<TP_BLKS + RESIZE_BLKS + NBLK, 256, 0, stream>>>(
        depths, mats, src_RTinvs, dst_RTs, zwin, feats, tf, colors, colr);
    gather3_k<<<3 * NBLK, 256, 0, stream>>>(zwin, tf, colr, out0, out1, out2);
  } else {
    work_fb_k<<<RESIZE_BLKS + NBLK, 256, 0, stream>>>(
        depths, mats, src_RTinvs, dst_RTs, zwin, colors, colr);
    gather_k<<<5 * NBLK, 256, 0, stream>>>(zwin, feats, colr, out0, out1, out2);
  }
}

// Round 9
// 177.531 us; speedup vs baseline: 1.1988x; 1.1988x over previous
//
#include <hip/hip_runtime.h>
#include <hip/hip_fp16.h>
#include <stdint.h>

#pragma clang fp contract(off)

namespace {
constexpr int B_ = 2, V_ = 2, HC = 512, WC = 512, HF = 256, WF = 256, CF = 64;
constexpr int NPIX = HF * WF;                 // 65536
constexpr float EPSF = 1e-4f;
constexpr float BIGF = 1e10f;                 // exactly representable in f32
constexpr int NPT = B_ * V_ * NPIX;           // 262144
constexpr int NBLK = 1024;                    // NPT/256
constexpr int RESIZE_BLKS = (B_ * V_ * 3 * NPIX) / 256;   // 3072
constexpr int TP_BLKS = B_ * V_ * (NPIX / 64);            // 4096 (64px x 64ch tiles)
// workspace layout: zwin (2 MiB) | colr (3 MiB) | mats (256 B) | tf fp16 (32 MiB)
constexpr size_t WS_BASE = (size_t)NPT * 8 + (size_t)B_ * V_ * 3 * NPIX * 4 + 256;
constexpr size_t TF_BYTES = (size_t)NPT * CF * 2;          // fp16 records
}

// NON-FMA ascending f32 dot4 (fp contract off TU-wide keeps mul/add separate).
__device__ __forceinline__ float dot4f(const float* __restrict__ r,
                                       float v0, float v1, float v2, float v3) {
  float t = r[0] * v0;
  t = t + r[1] * v1;
  t = t + r[2] * v2;
  t = t + r[3] * v3;
  return t;
}

// per-batch sK / sKinv (f64 adjugate -> f32). Executed by thread b (b < B_).
__device__ void mats_compute(const float* __restrict__ K, int b,
                             float* __restrict__ mats) {
  const float rowscale[4] = {0.5f, 0.5f, 1.0f, 1.0f};
  float sK[16];
  for (int i = 0; i < 4; ++i)
    for (int j = 0; j < 4; ++j)
      sK[i*4+j] = K[b*16 + i*4 + j] * rowscale[i];
  double m[16];
  for (int i = 0; i < 16; ++i) m[i] = (double)sK[i];
  double inv[16];
  inv[0]  =  m[5]*m[10]*m[15] - m[5]*m[11]*m[14] - m[9]*m[6]*m[15] + m[9]*m[7]*m[14] + m[13]*m[6]*m[11] - m[13]*m[7]*m[10];
  inv[4]  = -m[4]*m[10]*m[15] + m[4]*m[11]*m[14] + m[8]*m[6]*m[15] - m[8]*m[7]*m[14] - m[12]*m[6]*m[11] + m[12]*m[7]*m[10];
  inv[8]  =  m[4]*m[9]*m[15]  - m[4]*m[11]*m[13] - m[8]*m[5]*m[15] + m[8]*m[7]*m[13] + m[12]*m[5]*m[11] - m[12]*m[7]*m[9];
  inv[12] = -m[4]*m[9]*m[14]  + m[4]*m[10]*m[13] + m[8]*m[5]*m[14] - m[8]*m[6]*m[13] - m[12]*m[5]*m[10] + m[12]*m[6]*m[9];
  inv[1]  = -m[1]*m[10]*m[15] + m[1]*m[11]*m[14] + m[9]*m[2]*m[15] - m[9]*m[3]*m[14] - m[13]*m[2]*m[11] + m[13]*m[3]*m[10];
  inv[5]  =  m[0]*m[10]*m[15] - m[0]*m[11]*m[14] - m[8]*m[2]*m[15] + m[8]*m[3]*m[14] + m[12]*m[2]*m[11] - m[12]*m[3]*m[10];
  inv[9]  = -m[0]*m[9]*m[15]  + m[0]*m[11]*m[13] + m[8]*m[1]*m[15] - m[8]*m[3]*m[13] - m[12]*m[1]*m[11] + m[12]*m[3]*m[9];
  inv[13] =  m[0]*m[9]*m[14]  - m[0]*m[10]*m[13] - m[8]*m[1]*m[14] + m[8]*m[2]*m[13] + m[12]*m[1]*m[10] - m[12]*m[2]*m[9];
  inv[2]  =  m[1]*m[6]*m[15]  - m[1]*m[7]*m[14]  - m[5]*m[2]*m[15] + m[5]*m[3]*m[14] + m[13]*m[2]*m[7]  - m[13]*m[3]*m[6];
  inv[6]  = -m[0]*m[6]*m[15]  + m[0]*m[7]*m[14]  + m[4]*m[2]*m[15] - m[4]*m[3]*m[14] - m[12]*m[2]*m[7]  + m[12]*m[3]*m[6];
  inv[10] =  m[0]*m[5]*m[15]  - m[0]*m[7]*m[13]  - m[4]*m[1]*m[15] + m[4]*m[3]*m[13] + m[12]*m[1]*m[7]  - m[12]*m[3]*m[5];
  inv[14] = -m[0]*m[5]*m[14]  + m[0]*m[6]*m[13]  + m[4]*m[1]*m[14] - m[4]*m[2]*m[13] - m[12]*m[1]*m[6]  + m[12]*m[2]*m[5];
  inv[3]  = -m[1]*m[6]*m[11]  + m[1]*m[7]*m[10]  + m[5]*m[2]*m[11] - m[5]*m[3]*m[10] - m[9]*m[2]*m[7]   + m[9]*m[3]*m[6];
  inv[7]  =  m[0]*m[6]*m[11]  - m[0]*m[7]*m[10]  - m[4]*m[2]*m[11] + m[4]*m[3]*m[10] + m[8]*m[2]*m[7]   - m[8]*m[3]*m[6];
  inv[11] = -m[0]*m[5]*m[11]  + m[0]*m[7]*m[9]   + m[4]*m[1]*m[11] - m[4]*m[3]*m[9]  - m[8]*m[1]*m[7]   + m[8]*m[3]*m[5];
  inv[15] =  m[0]*m[5]*m[10]  - m[0]*m[6]*m[9]   - m[4]*m[1]*m[10] + m[4]*m[2]*m[9]  + m[8]*m[1]*m[6]   - m[8]*m[2]*m[5];
  double det = m[0]*inv[0] + m[1]*inv[4] + m[2]*inv[8] + m[3]*inv[12];
  double idet = 1.0 / det;
  for (int i = 0; i < 16; ++i) {
    mats[b*32 + i]      = sK[i];
    mats[b*32 + 16 + i] = (float)(inv[i] * idet);
  }
}

// antialiased linear 2x downsample of colors (r5 arithmetic).
__device__ __forceinline__ void resize_body(int g,
                                            const float* __restrict__ colors,
                                            float* __restrict__ colr) {
  int pc  = g >> 16;            // bv*3 + ch
  int pix = g & (NPIX - 1);
  int y = pix >> 8, x = pix & (WF - 1);
  const float* src = colors + (size_t)pc * HC * WC;
  const float W37 = (float)(3.0 / 7.0), W17 = (float)(1.0 / 7.0);
  float wy[4] = {0.125f, 0.375f, 0.375f, 0.125f};
  float wx[4] = {0.125f, 0.375f, 0.375f, 0.125f};
  if (y == 0)      { wy[0] = 0.f; wy[1] = W37; wy[2] = W37; wy[3] = W17; }
  if (y == HF - 1) { wy[0] = W17; wy[1] = W37; wy[2] = W37; wy[3] = 0.f; }
  if (x == 0)      { wx[0] = 0.f; wx[1] = W37; wx[2] = W37; wx[3] = W17; }
  if (x == WF - 1) { wx[0] = W17; wx[1] = W37; wx[2] = W37; wx[3] = 0.f; }
  int jy0 = 2 * y - 1, jx0 = 2 * x - 1;
  float acc = 0.f;
  #pragma unroll
  for (int ty = 0; ty < 4; ++ty) {
    if (wy[ty] == 0.f) continue;       // also guards OOB rows
    int jy = jy0 + ty;
    float rs = 0.f;
    #pragma unroll
    for (int tx = 0; tx < 4; ++tx) {
      if (wx[tx] == 0.f) continue;     // also guards OOB cols
      rs = rs + wx[tx] * src[(size_t)jy * WC + (jx0 + tx)];
    }
    acc = acc + wy[ty] * rs;
  }
  colr[g] = acc;
}

// f32 projection + z-buffer atomicMin (r5 PASSING numerics — do not touch).
__device__ __forceinline__ void splat_body(int g,
                                           const float* __restrict__ depths,
                                           const float* __restrict__ mats,
                                           const float* __restrict__ srcRTinv,
                                           const float* __restrict__ dstRT,
                                           unsigned long long* __restrict__ zwin) {
  int bv = g >> 16;
  int n  = g & (NPIX - 1);
  int b  = bv / V_;
  int y = n >> 8, x = n & (WF - 1);
  float d = depths[(size_t)bv * HC * WC + (size_t)(2 * y + 1) * WC + (2 * x + 1)];
  const float step32 = 2.0f / 255.0f;
  float xf = (float)x * step32 - 1.0f;
  float yf = (float)y * step32 - 1.0f;
  float pr0 = xf * d, pr1 = yf * d, pr2 = d, pr3 = 1.0f;
  const float* sK  = mats + b * 32;
  const float* sKi = mats + b * 32 + 16;
  const float* Rs  = srcRTinv + (size_t)bv * 16;
  const float* Rd  = dstRT + (size_t)b * 16;     // dst_RTs[:,0]
  float a0 = dot4f(sKi + 0,  pr0, pr1, pr2, pr3);
  float a1 = dot4f(sKi + 4,  pr0, pr1, pr2, pr3);
  float a2 = dot4f(sKi + 8,  pr0, pr1, pr2, pr3);
  float a3 = dot4f(sKi + 12, pr0, pr1, pr2, pr3);
  float w0 = dot4f(Rs + 0,  a0, a1, a2, a3);
  float w1 = dot4f(Rs + 4,  a0, a1, a2, a3);
  float w2 = dot4f(Rs + 8,  a0, a1, a2, a3);
  float w3 = dot4f(Rs + 12, a0, a1, a2, a3);
  float c0 = dot4f(Rd + 0,  w0, w1, w2, w3);
  float c1 = dot4f(Rd + 4,  w0, w1, w2, w3);
  float c2 = dot4f(Rd + 8,  w0, w1, w2, w3);
  float c3 = dot4f(Rd + 12, w0, w1, w2, w3);
  float p0 = dot4f(sK + 0, c0, c1, c2, c3);
  float p1 = dot4f(sK + 4, c0, c1, c2, c3);
  float p2 = dot4f(sK + 8, c0, c1, c2, c3);
  if (p2 > EPSF) {
    float sx = p0 / p2, sy = p1 / p2;                 // f32 IEEE division
    float pxf = rintf(((sx + 1.0f) * 0.5f) * 255.0f); // jnp.round = half-to-even
    float pyf = rintf(((sy + 1.0f) * 0.5f) * 255.0f);
    if (pxf >= 0.0f && pxf <= 255.0f && pyf >= 0.0f && pyf <= 255.0f) {
      int idx = (int)pyf * WF + (int)pxf;
      unsigned zbits = __float_as_uint(p2);           // p2>0 -> order-preserving
      unsigned long long key = ((unsigned long long)zbits << 32) | (unsigned)n;
      atomicMin(&zwin[(size_t)bv * NPIX + idx], key);
    }
  }
}

// --- tiny: per-batch matrices only (zwin init moved to hipMemsetAsync) ---
__global__ void mats_k(const float* __restrict__ K, float* __restrict__ mats) {
  int t = threadIdx.x;
  if (t < B_) mats_compute(K, t, mats);
}

// --- fused work: fp16 transpose + resize + splat (mutually independent).
// Transpose blocks [0, TP_BLKS): (bv,c,pix)->(bv,pix,c) fp16 records,
//   4x4 reg micro-tile, 8B uint2 packed stores (r8-verified, passing).
// Blocks [TP_BLKS, +3072): resize.  Blocks [.., +1024): splat.
__global__ void work_k(const float* __restrict__ depths,
                       const float* __restrict__ mats,
                       const float* __restrict__ srcRTinv,
                       const float* __restrict__ dstRT,
                       unsigned long long* __restrict__ zwin,
                       const float* __restrict__ feats,
                       __half* __restrict__ tf,
                       const float* __restrict__ colors,
                       float* __restrict__ colr) {
  int bid = blockIdx.x;
  int nTP = (int)gridDim.x - RESIZE_BLKS - NBLK;
  int t = threadIdx.x;

  if (bid < nTP) {                     // ---- transpose (fp16 out) ----
    int bv = bid >> 10;                // 1024 tiles per bv (64 px each)
    int pix0 = (bid & 1023) << 6;
    int c4 = t >> 4;                   // 0..15 -> channels 4*c4..4*c4+3
    int p4 = t & 15;                   // 0..15 -> pixels 4*p4..4*p4+3
    const float* fb = feats + (size_t)bv * CF * NPIX + pix0 + 4 * p4;
    float4 v0 = *(const float4*)(fb + (size_t)(4 * c4 + 0) * NPIX);
    float4 v1 = *(const float4*)(fb + (size_t)(4 * c4 + 1) * NPIX);
    float4 v2 = *(const float4*)(fb + (size_t)(4 * c4 + 2) * NPIX);
    float4 v3 = *(const float4*)(fb + (size_t)(4 * c4 + 3) * NPIX);
    __half* tb = tf + ((size_t)bv * NPIX + pix0 + 4 * p4) * CF + 4 * c4;
    union { __half h[4]; uint2 u; } pk;
    pk.h[0] = __float2half(v0.x); pk.h[1] = __float2half(v1.x);
    pk.h[2] = __float2half(v2.x); pk.h[3] = __float2half(v3.x);
    *(uint2*)(tb + 0 * CF) = pk.u;
    pk.h[0] = __float2half(v0.y); pk.h[1] = __float2half(v1.y);
    pk.h[2] = __float2half(v2.y); pk.h[3] = __float2half(v3.y);
    *(uint2*)(tb + 1 * CF) = pk.u;
    pk.h[0] = __float2half(v0.z); pk.h[1] = __float2half(v1.z);
    pk.h[2] = __float2half(v2.z); pk.h[3] = __float2half(v3.z);
    *(uint2*)(tb + 2 * CF) = pk.u;
    pk.h[0] = __float2half(v0.w); pk.h[1] = __float2half(v1.w);
    pk.h[2] = __float2half(v2.w); pk.h[3] = __float2half(v3.w);
    *(uint2*)(tb + 3 * CF) = pk.u;
    return;
  }

  int rb = bid - nTP;
  if (rb < RESIZE_BLKS) {              // ---- color resize ----
    resize_body(rb * 256 + t, colors, colr);
    return;
  }

  // ---- splat ----
  int g = (rb - RESIZE_BLKS) * 256 + t;
  splat_body(g, depths, mats, srcRTinv, dstRT, zwin);
}

// --- BRANCHLESS gather from fp16 records, 3 block-groups.
// r8 showed 123 MB writes vs 71 ideal: divergent hit/miss branches emit TWO
// partial-mask nt stores per output line (hit lanes + miss lanes), each sent
// to HBM separately. Fix: unconditional loads (record 0 for misses) +
// cndmask/multiply select -> ONE full-wave store per plane.
__global__ void gather3_k(const unsigned long long* __restrict__ zwin,
                          const __half* __restrict__ tf,
                          const float* __restrict__ colr,
                          float* __restrict__ out0,
                          float* __restrict__ out1,
                          float* __restrict__ out2) {
  int bid = blockIdx.x;
  int grp = bid >> 10;
  int g   = (bid & (NBLK - 1)) * 256 + threadIdx.x;
  int bv  = g >> 16;
  int pix = g & (NPIX - 1);
  unsigned long long key = zwin[g];
  bool hit = (key != ~0ULL);
  int n = hit ? (int)(key & 0xffffffffULL) : 0;   // safe load index for misses
  float s = hit ? 1.0f : 0.0f;

  if (grp < 2) {                       // 32 feat channels = 64B of fp16
    // byte offset = n*128 + 64*grp -> 16B aligned
    const float4* src =
        (const float4*)(tf + ((size_t)bv * NPIX + n) * CF + grp * 32);
    float4 raw[4];
    #pragma unroll
    for (int i = 0; i < 4; ++i) raw[i] = src[i];
    float* o0 = out0 + (size_t)bv * CF * NPIX + (size_t)(grp * 32) * NPIX + pix;
    const __half* hp = (const __half*)raw;
    #pragma unroll
    for (int c = 0; c < 32; ++c)       // s==0 -> exact +0.0 (tf values finite)
      __builtin_nontemporal_store(__half2float(hp[c]) * s, &o0[(size_t)c * NPIX]);
  } else {                             // colors + depth
    int b = bv >> 1, v = bv & 1;
    const float* cb = colr + (size_t)bv * 3 * NPIX;
    float* o1 = out1 + (size_t)(v * B_ + b) * 3 * NPIX + pix;
    float zraw = __uint_as_float((unsigned)(key >> 32));   // miss -> NaN
    float zval = (hit && zraw < BIGF) ? zraw : 0.0f;       // NaN<x false -> 0
    __builtin_nontemporal_store(zval, &out2[g]);
    #pragma unroll
    for (int ch = 0; ch < 3; ++ch) {
      float cv = cb[(size_t)ch * NPIX + n] * 0.5f + 0.5f;
      __builtin_nontemporal_store(hit ? cv : 0.0f, &o1[(size_t)ch * NPIX]);
    }
  }
}

// --- no-tf fallback: resize+splat fused, then fp32 direct gather (r0) ---
__global__ void work_fb_k(const float* __restrict__ depths,
                          const float* __restrict__ mats,
                          const float* __restrict__ srcRTinv,
                          const float* __restrict__ dstRT,
                          unsigned long long* __restrict__ zwin,
                          const float* __restrict__ colors,
                          float* __restrict__ colr) {
  int bid = blockIdx.x;
  int t = threadIdx.x;
  if (bid < RESIZE_BLKS) { resize_body(bid * 256 + t, colors, colr); return; }
  int g = (bid - RESIZE_BLKS) * 256 + t;
  splat_body(g, depths, mats, srcRTinv, dstRT, zwin);
}

__global__ void gather_k(const unsigned long long* __restrict__ zwin,
                         const float* __restrict__ feats,
                         const float* __restrict__ colr,
                         float* __restrict__ out0,
                         float* __restrict__ out1,
                         float* __restrict__ out2) {
  int bid = blockIdx.x;
  int grp = bid >> 10;
  int g   = (bid & (NBLK - 1)) * 256 + threadIdx.x;
  int bv  = g >> 16;
  int pix = g & (NPIX - 1);
  unsigned long long key = zwin[g];
  bool hit = (key != ~0ULL);
  int n = hit ? (int)(key & 0xffffffffULL) : 0;
  float s = hit ? 1.0f : 0.0f;

  if (grp < 4) {
    int c0 = grp * 16;
    const float* fb = feats + (size_t)bv * CF * NPIX + (size_t)c0 * NPIX;
    float* o0 = out0 + (size_t)bv * CF * NPIX + (size_t)c0 * NPIX + pix;
    #pragma unroll
    for (int c = 0; c < 16; ++c)
      __builtin_nontemporal_store(fb[(size_t)c * NPIX + n] * s,
                                  &o0[(size_t)c * NPIX]);
  } else {
    int b = bv >> 1, v = bv & 1;
    const float* cb = colr + (size_t)bv * 3 * NPIX;
    float* o1 = out1 + (size_t)(v * B_ + b) * 3 * NPIX + pix;
    float zraw = __uint_as_float((unsigned)(key >> 32));
    float zval = (hit && zraw < BIGF) ? zraw : 0.0f;
    __builtin_nontemporal_store(zval, &out2[g]);
    #pragma unroll
    for (int ch = 0; ch < 3; ++ch) {
      float cv = cb[(size_t)ch * NPIX + n] * 0.5f + 0.5f;
      __builtin_nontemporal_store(hit ? cv : 0.0f, &o1[(size_t)ch * NPIX]);
    }
  }
}

extern "C" void kernel_launch(void* const* d_in, const int* in_sizes, int n_in,
                              void* d_out, int out_size, void* d_ws, size_t ws_size,
                              hipStream_t stream) {
  const float* depths     = (const float*)d_in[0];
  const float* colors     = (const float*)d_in[1];
  const float* feats      = (const float*)d_in[2];
  const float* K          = (const float*)d_in[3];
  const float* src_RTinvs = (const float*)d_in[5];
  const float* dst_RTs    = (const float*)d_in[6];

  float* out0 = (float*)d_out;                                  // (B,V,64,256,256)
  float* out1 = out0 + (size_t)B_ * V_ * CF * NPIX;             // (V,B,3,256,256)
  float* out2 = out1 + (size_t)V_ * B_ * 3 * NPIX;              // (B,V,1,256,256)

  unsigned long long* zwin = (unsigned long long*)d_ws;         // 2 MiB
  float* colr = (float*)(zwin + NPT);                           // 3 MiB
  float* mats = colr + (size_t)B_ * V_ * 3 * NPIX;              // 256 B
  __half* tf  = (__half*)((char*)d_ws + WS_BASE);               // 32 MiB fp16

  const bool use_tf = (ws_size >= WS_BASE + TF_BYTES);

  // zwin = all 0xFF bytes == ~0ULL keys (runtime fill ~6.5 TB/s, capture-safe)
  hipMemsetAsync(zwin, 0xFF, (size_t)NPT * 8, stream);
  mats_k<<<1, 64, 0, stream>>>(K, mats);
  if (use_tf) {
    work_k<<<TP_BLKS + RESIZE_BLKS + NBLK, 256, 0, stream>>>(
        depths, mats, src_RTinvs, dst_RTs, zwin, feats, tf, colors, colr);
    gather3_k<<<3 * NBLK, 256, 0, stream>>>(zwin, tf, colr, out0, out1, out2);
  } else {
    work_fb_k<<<RESIZE_BLKS + NBLK, 256, 0, stream>>>(
        depths, mats, src_RTinvs, dst_RTs, zwin, colors, colr);
    gather_k<<<5 * NBLK, 256, 0, stream>>>(zwin, feats, colr, out0, out1, out2);
  }
}

// Round 12
// 175.990 us; speedup vs baseline: 1.2093x; 1.0088x over previous
//
#include <hip/hip_runtime.h>
#include <hip/hip_fp16.h>
#include <stdint.h>

#pragma clang fp contract(off)

namespace {
constexpr int B_ = 2, V_ = 2, HC = 512, WC = 512, HF = 256, WF = 256, CF = 64;
constexpr int NPIX = HF * WF;                 // 65536
constexpr float EPSF = 1e-4f;
constexpr float BIGF = 1e10f;                 // exactly representable in f32
constexpr int NPT = B_ * V_ * NPIX;           // 262144
constexpr int NBLK = 1024;                    // NPT/256
constexpr int RESIZE_QB = (B_ * V_ * 3 * NPIX / 4) / 256; // 768 (4 px/thread)
constexpr int TP_BLKS = B_ * V_ * (NPIX / 64);            // 4096 (64px x 64ch tiles)
// workspace layout: zwin (2 MiB) | colr (3 MiB) | mats (256 B) | tf fp16 (32 MiB)
constexpr size_t WS_BASE = (size_t)NPT * 8 + (size_t)B_ * V_ * 3 * NPIX * 4 + 256;
constexpr size_t TF_BYTES = (size_t)NPT * CF * 2;          // fp16 records
}

typedef float f32x4 __attribute__((ext_vector_type(4)));   // nt-store-compatible

// NON-FMA ascending f32 dot4 (fp contract off TU-wide keeps mul/add separate).
__device__ __forceinline__ float dot4f(const float* __restrict__ r,
                                       float v0, float v1, float v2, float v3) {
  float t = r[0] * v0;
  t = t + r[1] * v1;
  t = t + r[2] * v2;
  t = t + r[3] * v3;
  return t;
}

// per-batch sK / sKinv (f64 adjugate -> f32). Executed by thread b (b < B_).
__device__ void mats_compute(const float* __restrict__ K, int b,
                             float* __restrict__ mats) {
  const float rowscale[4] = {0.5f, 0.5f, 1.0f, 1.0f};
  float sK[16];
  for (int i = 0; i < 4; ++i)
    for (int j = 0; j < 4; ++j)
      sK[i*4+j] = K[b*16 + i*4 + j] * rowscale[i];
  double m[16];
  for (int i = 0; i < 16; ++i) m[i] = (double)sK[i];
  double inv[16];
  inv[0]  =  m[5]*m[10]*m[15] - m[5]*m[11]*m[14] - m[9]*m[6]*m[15] + m[9]*m[7]*m[14] + m[13]*m[6]*m[11] - m[13]*m[7]*m[10];
  inv[4]  = -m[4]*m[10]*m[15] + m[4]*m[11]*m[14] + m[8]*m[6]*m[15] - m[8]*m[7]*m[14] - m[12]*m[6]*m[11] + m[12]*m[7]*m[10];
  inv[8]  =  m[4]*m[9]*m[15]  - m[4]*m[11]*m[13] - m[8]*m[5]*m[15] + m[8]*m[7]*m[13] + m[12]*m[5]*m[11] - m[12]*m[7]*m[9];
  inv[12] = -m[4]*m[9]*m[14]  + m[4]*m[10]*m[13] + m[8]*m[5]*m[14] - m[8]*m[6]*m[13] - m[12]*m[5]*m[10] + m[12]*m[6]*m[9];
  inv[1]  = -m[1]*m[10]*m[15] + m[1]*m[11]*m[14] + m[9]*m[2]*m[15] - m[9]*m[3]*m[14] - m[13]*m[2]*m[11] + m[13]*m[3]*m[10];
  inv[5]  =  m[0]*m[10]*m[15] - m[0]*m[11]*m[14] - m[8]*m[2]*m[15] + m[8]*m[3]*m[14] + m[12]*m[2]*m[11] - m[12]*m[3]*m[10];
  inv[9]  = -m[0]*m[9]*m[15]  + m[0]*m[11]*m[13] + m[8]*m[1]*m[15] - m[8]*m[3]*m[13] - m[12]*m[1]*m[11] + m[12]*m[3]*m[9];
  inv[13] =  m[0]*m[9]*m[14]  - m[0]*m[10]*m[13] - m[8]*m[1]*m[14] + m[8]*m[2]*m[13] + m[12]*m[1]*m[10] - m[12]*m[2]*m[9];
  inv[2]  =  m[1]*m[6]*m[15]  - m[1]*m[7]*m[14]  - m[5]*m[2]*m[15] + m[5]*m[3]*m[14] + m[13]*m[2]*m[7]  - m[13]*m[3]*m[6];
  inv[6]  = -m[0]*m[6]*m[15]  + m[0]*m[7]*m[14]  + m[4]*m[2]*m[15] - m[4]*m[3]*m[14] - m[12]*m[2]*m[7]  + m[12]*m[3]*m[6];
  inv[10] =  m[0]*m[5]*m[15]  - m[0]*m[7]*m[13]  - m[4]*m[1]*m[15] + m[4]*m[3]*m[13] + m[12]*m[1]*m[7]  - m[12]*m[3]*m[5];
  inv[14] = -m[0]*m[5]*m[14]  + m[0]*m[6]*m[13]  + m[4]*m[1]*m[14] - m[4]*m[2]*m[13] - m[12]*m[1]*m[6]  + m[12]*m[2]*m[5];
  inv[3]  = -m[1]*m[6]*m[11]  + m[1]*m[7]*m[10]  + m[5]*m[2]*m[11] - m[5]*m[3]*m[10] - m[9]*m[2]*m[7]   + m[9]*m[3]*m[6];
  inv[7]  =  m[0]*m[6]*m[11]  - m[0]*m[7]*m[10]  - m[4]*m[2]*m[11] + m[4]*m[3]*m[10] + m[8]*m[2]*m[7]   - m[8]*m[3]*m[6];
  inv[11] = -m[0]*m[5]*m[11]  + m[0]*m[7]*m[9]   + m[4]*m[1]*m[11] - m[4]*m[3]*m[9]  - m[8]*m[1]*m[7]   + m[8]*m[3]*m[5];
  inv[15] =  m[0]*m[5]*m[10]  - m[0]*m[6]*m[9]   - m[4]*m[1]*m[10] + m[4]*m[2]*m[9]  + m[8]*m[1]*m[6]   - m[8]*m[2]*m[5];
  double det = m[0]*inv[0] + m[1]*inv[4] + m[2]*inv[8] + m[3]*inv[12];
  double idet = 1.0 / det;
  for (int i = 0; i < 16; ++i) {
    mats[b*32 + i]      = sK[i];
    mats[b*32 + 16 + i] = (float)(inv[i] * idet);
  }
}

// antialiased linear 2x downsample, ONE output pixel (r5 arithmetic, exact).
__device__ __forceinline__ void resize_body(int g,
                                            const float* __restrict__ colors,
                                            float* __restrict__ colr) {
  int pc  = g >> 16;            // bv*3 + ch
  int pix = g & (NPIX - 1);
  int y = pix >> 8, x = pix & (WF - 1);
  const float* src = colors + (size_t)pc * HC * WC;
  const float W37 = (float)(3.0 / 7.0), W17 = (float)(1.0 / 7.0);
  float wy[4] = {0.125f, 0.375f, 0.375f, 0.125f};
  float wx[4] = {0.125f, 0.375f, 0.375f, 0.125f};
  if (y == 0)      { wy[0] = 0.f; wy[1] = W37; wy[2] = W37; wy[3] = W17; }
  if (y == HF - 1) { wy[0] = W17; wy[1] = W37; wy[2] = W37; wy[3] = 0.f; }
  if (x == 0)      { wx[0] = 0.f; wx[1] = W37; wx[2] = W37; wx[3] = W17; }
  if (x == WF - 1) { wx[0] = W17; wx[1] = W37; wx[2] = W37; wx[3] = 0.f; }
  int jy0 = 2 * y - 1, jx0 = 2 * x - 1;
  float acc = 0.f;
  #pragma unroll
  for (int ty = 0; ty < 4; ++ty) {
    if (wy[ty] == 0.f) continue;       // also guards OOB rows
    int jy = jy0 + ty;
    float rs = 0.f;
    #pragma unroll
    for (int tx = 0; tx < 4; ++tx) {
      if (wx[tx] == 0.f) continue;     // also guards OOB cols
      rs = rs + wx[tx] * src[(size_t)jy * WC + (jx0 + tx)];
    }
    acc = acc + wy[ty] * rs;
  }
  colr[g] = acc;
}

// resize, FOUR consecutive output pixels via float4 row loads.
// r9 counters showed work_k is VMEM-ISSUE bound: scalar resize = 17 VMEM/px.
// This path: 16 loads + 1 store per 4 px (4.25/px). Per-pixel accumulation
// order identical to resize_body (all-nonzero interior wx, ascending taps)
// -> bit-identical. x0 in {0,252} falls back to scalar (OOB/edge weights).
__device__ __forceinline__ void resize_quad(int gq,
                                            const float* __restrict__ colors,
                                            float* __restrict__ colr) {
  int pc  = gq >> 14;                  // NPIX/4 = 16384 quads per plane
  int pix = (gq & 16383) << 2;
  int y = pix >> 8, x0 = pix & (WF - 1);   // x0 multiple of 4
  if (x0 == 0 || x0 == WF - 4) {       // edge columns: exact scalar path
    int g = pc * NPIX + pix;
    #pragma unroll
    for (int k = 0; k < 4; ++k) resize_body(g + k, colors, colr);
    return;
  }
  const float* src = colors + (size_t)pc * HC * WC;
  const float W37 = (float)(3.0 / 7.0), W17 = (float)(1.0 / 7.0);
  float wy[4] = {0.125f, 0.375f, 0.375f, 0.125f};
  if (y == 0)      { wy[0] = 0.f; wy[1] = W37; wy[2] = W37; wy[3] = W17; }
  if (y == HF - 1) { wy[0] = W17; wy[1] = W37; wy[2] = W37; wy[3] = 0.f; }
  const float wx0 = 0.125f, wx1 = 0.375f, wx2 = 0.375f, wx3 = 0.125f;
  int jy0 = 2 * y - 1;
  float acc0 = 0.f, acc1 = 0.f, acc2 = 0.f, acc3 = 0.f;
  #pragma unroll
  for (int ty = 0; ty < 4; ++ty) {
    if (wy[ty] == 0.f) continue;       // also guards OOB rows
    const float* row = src + (size_t)(jy0 + ty) * WC + 2 * x0;
    float4 a = *(const float4*)(row - 4);   // cols 2x0-4 .. 2x0-1 (16B aligned)
    float4 b = *(const float4*)(row);       // 2x0   .. 2x0+3
    float4 c = *(const float4*)(row + 4);   // 2x0+4 .. 2x0+7
    float4 d = *(const float4*)(row + 8);   // 2x0+8 .. 2x0+11
    float rs;
    rs = wx0 * a.w; rs = rs + wx1 * b.x; rs = rs + wx2 * b.y; rs = rs + wx3 * b.z;
    acc0 = acc0 + wy[ty] * rs;
    rs = wx0 * b.y; rs = rs + wx1 * b.z; rs = rs + wx2 * b.w; rs = rs + wx3 * c.x;
    acc1 = acc1 + wy[ty] * rs;
    rs = wx0 * b.w; rs = rs + wx1 * c.x; rs = rs + wx2 * c.y; rs = rs + wx3 * c.z;
    acc2 = acc2 + wy[ty] * rs;
    rs = wx0 * c.y; rs = rs + wx1 * c.z; rs = rs + wx2 * c.w; rs = rs + wx3 * d.x;
    acc3 = acc3 + wy[ty] * rs;
  }
  *(float4*)(colr + (size_t)pc * NPIX + pix) = make_float4(acc0, acc1, acc2, acc3);
}

// f32 projection + z-buffer atomicMin (r5 PASSING numerics — do not touch).
__device__ __forceinline__ void splat_body(int g,
                                           const float* __restrict__ depths,
                                           const float* __restrict__ mats,
                                           const float* __restrict__ srcRTinv,
                                           const float* __restrict__ dstRT,
                                           unsigned long long* __restrict__ zwin) {
  int bv = g >> 16;
  int n  = g & (NPIX - 1);
  int b  = bv / V_;
  int y = n >> 8, x = n & (WF - 1);
  float d = depths[(size_t)bv * HC * WC + (size_t)(2 * y + 1) * WC + (2 * x + 1)];
  const float step32 = 2.0f / 255.0f;
  float xf = (float)x * step32 - 1.0f;
  float yf = (float)y * step32 - 1.0f;
  float pr0 = xf * d, pr1 = yf * d, pr2 = d, pr3 = 1.0f;
  const float* sK  = mats + b * 32;
  const float* sKi = mats + b * 32 + 16;
  const float* Rs  = srcRTinv + (size_t)bv * 16;
  const float* Rd  = dstRT + (size_t)b * 16;     // dst_RTs[:,0]
  float a0 = dot4f(sKi + 0,  pr0, pr1, pr2, pr3);
  float a1 = dot4f(sKi + 4,  pr0, pr1, pr2, pr3);
  float a2 = dot4f(sKi + 8,  pr0, pr1, pr2, pr3);
  float a3 = dot4f(sKi + 12, pr0, pr1, pr2, pr3);
  float w0 = dot4f(Rs + 0,  a0, a1, a2, a3);
  float w1 = dot4f(Rs + 4,  a0, a1, a2, a3);
  float w2 = dot4f(Rs + 8,  a0, a1, a2, a3);
  float w3 = dot4f(Rs + 12, a0, a1, a2, a3);
  float c0 = dot4f(Rd + 0,  w0, w1, w2, w3);
  float c1 = dot4f(Rd + 4,  w0, w1, w2, w3);
  float c2 = dot4f(Rd + 8,  w0, w1, w2, w3);
  float c3 = dot4f(Rd + 12, w0, w1, w2, w3);
  float p0 = dot4f(sK + 0, c0, c1, c2, c3);
  float p1 = dot4f(sK + 4, c0, c1, c2, c3);
  float p2 = dot4f(sK + 8, c0, c1, c2, c3);
  if (p2 > EPSF) {
    float sx = p0 / p2, sy = p1 / p2;                 // f32 IEEE division
    float pxf = rintf(((sx + 1.0f) * 0.5f) * 255.0f); // jnp.round = half-to-even
    float pyf = rintf(((sy + 1.0f) * 0.5f) * 255.0f);
    if (pxf >= 0.0f && pxf <= 255.0f && pyf >= 0.0f && pyf <= 255.0f) {
      int idx = (int)pyf * WF + (int)pxf;
      unsigned zbits = __float_as_uint(p2);           // p2>0 -> order-preserving
      unsigned long long key = ((unsigned long long)zbits << 32) | (unsigned)n;
      atomicMin(&zwin[(size_t)bv * NPIX + idx], key);
    }
  }
}

// --- tiny: per-batch matrices only (zwin init via hipMemsetAsync) ---
__global__ void mats_k(const float* __restrict__ K, float* __restrict__ mats) {
  int t = threadIdx.x;
  if (t < B_) mats_compute(K, t, mats);
}

// --- fused work: fp16 transpose + vectorized resize + splat.
// Blocks [0, TP_BLKS): transpose (r9-verified). [TP_BLKS,+768): resize x4.
// [.., +1024): splat.
__global__ void work_k(const float* __restrict__ depths,
                       const float* __restrict__ mats,
                       const float* __restrict__ srcRTinv,
                       const float* __restrict__ dstRT,
                       unsigned long long* __restrict__ zwin,
                       const float* __restrict__ feats,
                       __half* __restrict__ tf,
                       const float* __restrict__ colors,
                       float* __restrict__ colr) {
  int bid = blockIdx.x;
  int nTP = (int)gridDim.x - RESIZE_QB - NBLK;
  int t = threadIdx.x;

  if (bid < nTP) {                     // ---- transpose (fp16 out) ----
    int bv = bid >> 10;                // 1024 tiles per bv (64 px each)
    int pix0 = (bid & 1023) << 6;
    int c4 = t >> 4;                   // 0..15 -> channels 4*c4..4*c4+3
    int p4 = t & 15;                   // 0..15 -> pixels 4*p4..4*p4+3
    const float* fb = feats + (size_t)bv * CF * NPIX + pix0 + 4 * p4;
    float4 v0 = *(const float4*)(fb + (size_t)(4 * c4 + 0) * NPIX);
    float4 v1 = *(const float4*)(fb + (size_t)(4 * c4 + 1) * NPIX);
    float4 v2 = *(const float4*)(fb + (size_t)(4 * c4 + 2) * NPIX);
    float4 v3 = *(const float4*)(fb + (size_t)(4 * c4 + 3) * NPIX);
    __half* tb = tf + ((size_t)bv * NPIX + pix0 + 4 * p4) * CF + 4 * c4;
    union { __half h[4]; uint2 u; } pk;
    pk.h[0] = __float2half(v0.x); pk.h[1] = __float2half(v1.x);
    pk.h[2] = __float2half(v2.x); pk.h[3] = __float2half(v3.x);
    *(uint2*)(tb + 0 * CF) = pk.u;
    pk.h[0] = __float2half(v0.y); pk.h[1] = __float2half(v1.y);
    pk.h[2] = __float2half(v2.y); pk.h[3] = __float2half(v3.y);
    *(uint2*)(tb + 1 * CF) = pk.u;
    pk.h[0] = __float2half(v0.z); pk.h[1] = __float2half(v1.z);
    pk.h[2] = __float2half(v2.z); pk.h[3] = __float2half(v3.z);
    *(uint2*)(tb + 2 * CF) = pk.u;
    pk.h[0] = __float2half(v0.w); pk.h[1] = __float2half(v1.w);
    pk.h[2] = __float2half(v2.w); pk.h[3] = __float2half(v3.w);
    *(uint2*)(tb + 3 * CF) = pk.u;
    return;
  }

  int rb = bid - nTP;
  if (rb < RESIZE_QB) {                // ---- color resize (4 px/thread) ----
    resize_quad(rb * 256 + t, colors, colr);
    return;
  }

  // ---- splat ----
  int g = (rb - RESIZE_QB) * 256 + t;
  splat_body(g, depths, mats, srcRTinv, dstRT, zwin);
}

// --- gather, vectorized 4 px/thread for feat groups (VMEM-issue fix).
// Blocks [0,512): grp = bid>>8 (32-ch half), thread owns 4 consecutive dst
//   pixels: zwin loads + 16 record loads (4x64B) + 32 f32x4 nt-stores
//   (vs 128 scalar stores) — 3x fewer VMEM instructions.
// Blocks [512, 512+1024): colors (V,B,3,H,W) + depth, 1 px/thread, branchless.
__global__ void gather3_k(const unsigned long long* __restrict__ zwin,
                          const __half* __restrict__ tf,
                          const float* __restrict__ colr,
                          float* __restrict__ out0,
                          float* __restrict__ out1,
                          float* __restrict__ out2) {
  int bid = blockIdx.x;
  int t = threadIdx.x;

  if (bid < 512) {                     // ---- feat channels, 4 px/thread ----
    int grp = bid >> 8;                // 0/1 -> channels 32*grp..+31
    int q = (bid & 255) * 256 + t;     // quad id, 0..65535
    int bv = q >> 14;
    int pix = (q << 2) & (NPIX - 1);   // 4-aligned
    const unsigned long long* zp = zwin + ((size_t)bv << 16) + pix;
    unsigned long long k0 = zp[0], k1 = zp[1], k2 = zp[2], k3 = zp[3];
    bool h0 = k0 != ~0ULL, h1 = k1 != ~0ULL, h2 = k2 != ~0ULL, h3 = k3 != ~0ULL;
    int n0 = h0 ? (int)(unsigned)k0 : 0;
    int n1 = h1 ? (int)(unsigned)k1 : 0;
    int n2 = h2 ? (int)(unsigned)k2 : 0;
    int n3 = h3 ? (int)(unsigned)k3 : 0;
    float s0 = h0 ? 1.f : 0.f, s1 = h1 ? 1.f : 0.f;
    float s2 = h2 ? 1.f : 0.f, s3 = h3 ? 1.f : 0.f;
    const __half* base = tf + ((size_t)bv << 16) * CF + grp * 32;
    float4 r0[4], r1[4], r2[4], r3[4];
    const float4* p0 = (const float4*)(base + (size_t)n0 * CF);
    const float4* p1 = (const float4*)(base + (size_t)n1 * CF);
    const float4* p2 = (const float4*)(base + (size_t)n2 * CF);
    const float4* p3 = (const float4*)(base + (size_t)n3 * CF);
    #pragma unroll
    for (int i = 0; i < 4; ++i) { r0[i] = p0[i]; r1[i] = p1[i];
                                  r2[i] = p2[i]; r3[i] = p3[i]; }
    const __half* h0p = (const __half*)r0;
    const __half* h1p = (const __half*)r1;
    const __half* h2p = (const __half*)r2;
    const __half* h3p = (const __half*)r3;
    float* o0 = out0 + (size_t)bv * CF * NPIX + (size_t)(grp * 32) * NPIX + pix;
    #pragma unroll
    for (int c = 0; c < 32; ++c) {
      f32x4 v;
      v.x = __half2float(h0p[c]) * s0;
      v.y = __half2float(h1p[c]) * s1;
      v.z = __half2float(h2p[c]) * s2;
      v.w = __half2float(h3p[c]) * s3;
      __builtin_nontemporal_store(v, (f32x4*)&o0[(size_t)c * NPIX]);
    }
    return;
  }

  // ---- colors + depth (1 px/thread, branchless) ----
  int g = (bid - 512) * 256 + t;
  int bv  = g >> 16;
  int pix = g & (NPIX - 1);
  unsigned long long key = zwin[g];
  bool hit = (key != ~0ULL);
  int n = hit ? (int)(key & 0xffffffffULL) : 0;
  int b = bv >> 1, v = bv & 1;
  const float* cb = colr + (size_t)bv * 3 * NPIX;
  float* o1 = out1 + (size_t)(v * B_ + b) * 3 * NPIX + pix;
  float zraw = __uint_as_float((unsigned)(key >> 32));
  float zval = (hit && zraw < BIGF) ? zraw : 0.0f;
  __builtin_nontemporal_store(zval, &out2[g]);
  #pragma unroll
  for (int ch = 0; ch < 3; ++ch) {
    float cv = cb[(size_t)ch * NPIX + n] * 0.5f + 0.5f;
    __builtin_nontemporal_store(hit ? cv : 0.0f, &o1[(size_t)ch * NPIX]);
  }
}

// --- no-tf fallback: resize+splat fused, then fp32 planar gather ---
__global__ void work_fb_k(const float* __restrict__ depths,
                          const float* __restrict__ mats,
                          const float* __restrict__ srcRTinv,
                          const float* __restrict__ dstRT,
                          unsigned long long* __restrict__ zwin,
                          const float* __restrict__ colors,
                          float* __restrict__ colr) {
  int bid = blockIdx.x;
  int t = threadIdx.x;
  if (bid < RESIZE_QB) { resize_quad(bid * 256 + t, colors, colr); return; }
  int g = (bid - RESIZE_QB) * 256 + t;
  splat_body(g, depths, mats, srcRTinv, dstRT, zwin);
}

__global__ void gather_k(const unsigned long long* __restrict__ zwin,
                         const float* __restrict__ feats,
                         const float* __restrict__ colr,
                         float* __restrict__ out0,
                         float* __restrict__ out1,
                         float* __restrict__ out2) {
  int bid = blockIdx.x;
  int grp = bid >> 10;
  int g   = (bid & (NBLK - 1)) * 256 + threadIdx.x;
  int bv  = g >> 16;
  int pix = g & (NPIX - 1);
  unsigned long long key = zwin[g];
  bool hit = (key != ~0ULL);
  int n = hit ? (int)(key & 0xffffffffULL) : 0;
  float s = hit ? 1.0f : 0.0f;

  if (grp < 4) {
    int c0 = grp * 16;
    const float* fb = feats + (size_t)bv * CF * NPIX + (size_t)c0 * NPIX;
    float* o0 = out0 + (size_t)bv * CF * NPIX + (size_t)c0 * NPIX + pix;
    #pragma unroll
    for (int c = 0; c < 16; ++c)
      __builtin_nontemporal_store(fb[(size_t)c * NPIX + n] * s,
                                  &o0[(size_t)c * NPIX]);
  } else {
    int b = bv >> 1, v = bv & 1;
    const float* cb = colr + (size_t)bv * 3 * NPIX;
    float* o1 = out1 + (size_t)(v * B_ + b) * 3 * NPIX + pix;
    float zraw = __uint_as_float((unsigned)(key >> 32));
    float zval = (hit && zraw < BIGF) ? zraw : 0.0f;
    __builtin_nontemporal_store(zval, &out2[g]);
    #pragma unroll
    for (int ch = 0; ch < 3; ++ch) {
      float cv = cb[(size_t)ch * NPIX + n] * 0.5f + 0.5f;
      __builtin_nontemporal_store(hit ? cv : 0.0f, &o1[(size_t)ch * NPIX]);
    }
  }
}

extern "C" void kernel_launch(void* const* d_in, const int* in_sizes, int n_in,
                              void* d_out, int out_size, void* d_ws, size_t ws_size,
                              hipStream_t stream) {
  const float* depths     = (const float*)d_in[0];
  const float* colors     = (const float*)d_in[1];
  const float* feats      = (const float*)d_in[2];
  const float* K          = (const float*)d_in[3];
  const float* src_RTinvs = (const float*)d_in[5];
  const float* dst_RTs    = (const float*)d_in[6];

  float* out0 = (float*)d_out;                                  // (B,V,64,256,256)
  float* out1 = out0 + (size_t)B_ * V_ * CF * NPIX;             // (V,B,3,256,256)
  float* out2 = out1 + (size_t)V_ * B_ * 3 * NPIX;              // (B,V,1,256,256)

  unsigned long long* zwin = (unsigned long long*)d_ws;         // 2 MiB
  float* colr = (float*)(zwin + NPT);                           // 3 MiB
  float* mats = colr + (size_t)B_ * V_ * 3 * NPIX;              // 256 B
  __half* tf  = (__half*)((char*)d_ws + WS_BASE);               // 32 MiB fp16

  const bool use_tf = (ws_size >= WS_BASE + TF_BYTES);

  // zwin = all 0xFF bytes == ~0ULL keys (runtime fill ~6.5 TB/s, capture-safe)
  (void)hipMemsetAsync(zwin, 0xFF, (size_t)NPT * 8, stream);
  mats_k<<<1, 64, 0, stream>>>(K, mats);
  if (use_tf) {
    work_k<<<TP_BLKS + RESIZE_QB + NBLK, 256, 0, stream>>>(
        depths, mats, src_RTinvs, dst_RTs, zwin, feats, tf, colors, colr);
    gather3_k<<<512 + NBLK, 256, 0, stream>>>(zwin, tf, colr, out0, out1, out2);
  } else {
    work_fb_k<<<RESIZE_QB + NBLK, 256, 0, stream>>>(
        depths, mats, src_RTinvs, dst_RTs, zwin, colors, colr);
    gather_k<<<5 * NBLK, 256, 0, stream>>>(zwin, feats, colr, out0, out1, out2);
  }
}